// Round 2
// baseline (447.700 us; speedup 1.0000x reference)
//
#include <hip/hip_runtime.h>
#include <hip/hip_bf16.h>

// Problem constants
// B=32, T=512, D=64, V=60
// inputs: [0] input_ids int32 [32*512], [1] repr_tab f32 [60*64*64],
//         [2] W1 f32 [4096*64], [3] b1 f32 [64], [4] W2 f32 [64*60], [5] b2 f32 [60]
// output: logits f32 [32*60]

constexpr int LDP = 68;  // padded LDS row stride for the 256-thread kernels

// ---------------- helpers for 256-thread kernels (scan2/scan3) ----------------

__device__ __forceinline__ void stage64(float* __restrict__ dst, const float* __restrict__ src, int t) {
    const int i = t >> 2;
    const int seg = (t & 3) << 4;
    const float4* s4 = reinterpret_cast<const float4*>(src + i * 64 + seg);
    float4 r0 = s4[0], r1 = s4[1], r2 = s4[2], r3 = s4[3];
    float4* d = reinterpret_cast<float4*>(dst + i * LDP + seg);
    d[0] = r0; d[1] = r1; d[2] = r2; d[3] = r3;
}

__device__ __forceinline__ void unstage64(float* __restrict__ dst, const float* __restrict__ src, int t) {
    const int i = t >> 2;
    const int seg = (t & 3) << 4;
    const float4* s4 = reinterpret_cast<const float4*>(src + i * LDP + seg);
    float4 r0 = s4[0], r1 = s4[1], r2 = s4[2], r3 = s4[3];
    float4* d = reinterpret_cast<float4*>(dst + i * 64 + seg);
    d[0] = r0; d[1] = r1; d[2] = r2; d[3] = r3;
}

__device__ __forceinline__ void fma_row(float (&acc)[4], float s, const float4& b) {
    acc[0] += s * b.x; acc[1] += s * b.y; acc[2] += s * b.z; acc[3] += s * b.w;
}

// S <- Qn @ S  (both 64x64 in padded LDS). 256 threads, 4x4 tile each.
__device__ __forceinline__ void mm64(float* __restrict__ S, const float* __restrict__ Qn, int t) {
    const int tx = t & 15, ty = t >> 4;
    const int i0 = ty << 2;
    const int j0 = tx << 2;
    float acc[4][4];
#pragma unroll
    for (int r = 0; r < 4; ++r)
#pragma unroll
        for (int c = 0; c < 4; ++c) acc[r][c] = 0.f;

#pragma unroll
    for (int k4 = 0; k4 < 16; ++k4) {
        const int k = k4 << 2;
        float4 a0 = *reinterpret_cast<const float4*>(&Qn[(i0 + 0) * LDP + k]);
        float4 a1 = *reinterpret_cast<const float4*>(&Qn[(i0 + 1) * LDP + k]);
        float4 a2 = *reinterpret_cast<const float4*>(&Qn[(i0 + 2) * LDP + k]);
        float4 a3 = *reinterpret_cast<const float4*>(&Qn[(i0 + 3) * LDP + k]);
        float4 b0 = *reinterpret_cast<const float4*>(&S[(k + 0) * LDP + j0]);
        float4 b1 = *reinterpret_cast<const float4*>(&S[(k + 1) * LDP + j0]);
        float4 b2 = *reinterpret_cast<const float4*>(&S[(k + 2) * LDP + j0]);
        float4 b3 = *reinterpret_cast<const float4*>(&S[(k + 3) * LDP + j0]);
        fma_row(acc[0], a0.x, b0); fma_row(acc[0], a0.y, b1); fma_row(acc[0], a0.z, b2); fma_row(acc[0], a0.w, b3);
        fma_row(acc[1], a1.x, b0); fma_row(acc[1], a1.y, b1); fma_row(acc[1], a1.z, b2); fma_row(acc[1], a1.w, b3);
        fma_row(acc[2], a2.x, b0); fma_row(acc[2], a2.y, b1); fma_row(acc[2], a2.z, b2); fma_row(acc[2], a2.w, b3);
        fma_row(acc[3], a3.x, b0); fma_row(acc[3], a3.y, b1); fma_row(acc[3], a3.z, b2); fma_row(acc[3], a3.w, b3);
    }
    __syncthreads();
#pragma unroll
    for (int r = 0; r < 4; ++r) {
        *reinterpret_cast<float4*>(&S[(i0 + r) * LDP + j0]) =
            make_float4(acc[r][0], acc[r][1], acc[r][2], acc[r][3]);
    }
}

// ---------------- Kernel 1: barrier-free one-wave Householder QR ----------------
// 60 blocks x 64 threads. Lane l holds column l of A and row l of Q in registers.
// LAPACK sgeqr2 convention: beta = -sign(alpha)*norm, tau=(beta-alpha)/beta,
// v_i = x_i/(alpha-beta), v_k=1. Q accumulated forward: Q <- Q - tau*(Q v)v^T.
__global__ __launch_bounds__(64) void qr_kernel(const float* __restrict__ repr, float* __restrict__ qtab) {
    const int l = threadIdx.x;
    const int v = blockIdx.x;
    const float* src = repr + v * 4096;

    float a[64];   // column l of A
    float q[64];   // row l of Q accumulator
#pragma unroll
    for (int i = 0; i < 64; ++i) a[i] = src[i * 64 + l];   // coalesced per i
#pragma unroll
    for (int i = 0; i < 64; ++i) q[i] = (i == l) ? 1.f : 0.f;

#pragma unroll 1
    for (int k = 0; k < 64; ++k) {
        // broadcast column k of (updated) A to all lanes
        float vr[64];
#pragma unroll
        for (int i = 0; i < 64; ++i) vr[i] = __shfl(a[i], k);

        // alpha = vr[k]; sigma = sum_{i>k} vr[i]^2  (redundant on all lanes)
        float s0 = 0.f, s1 = 0.f, s2 = 0.f, s3 = 0.f;
#pragma unroll
        for (int i = 0; i < 64; i += 4) {
            s0 += (i     > k) ? vr[i]     * vr[i]     : 0.f;
            s1 += (i + 1 > k) ? vr[i + 1] * vr[i + 1] : 0.f;
            s2 += (i + 2 > k) ? vr[i + 2] * vr[i + 2] : 0.f;
            s3 += (i + 3 > k) ? vr[i + 3] * vr[i + 3] : 0.f;
        }
        float sigma = (s0 + s1) + (s2 + s3);
        float al = 0.f;
#pragma unroll
        for (int i = 0; i < 64; ++i) al = (i == k) ? vr[i] : al;

        float beta, tau, scl;
        if (sigma == 0.f) { beta = al; tau = 0.f; scl = 0.f; }
        else {
            beta = -copysignf(sqrtf(al * al + sigma), al);
            tau = (beta - al) / beta;
            scl = 1.f / (al - beta);
        }

        // finalize v: 0 below k, 1 at k, scaled above k
#pragma unroll
        for (int i = 0; i < 64; ++i) vr[i] = (i < k) ? 0.f : ((i == k) ? 1.f : vr[i] * scl);

        // trailing update of own column: a -= tau*(v^T a) * v
        float w0 = 0.f, w1 = 0.f, w2 = 0.f, w3 = 0.f;
#pragma unroll
        for (int i = 0; i < 64; i += 4) {
            w0 += vr[i] * a[i]; w1 += vr[i + 1] * a[i + 1];
            w2 += vr[i + 2] * a[i + 2]; w3 += vr[i + 3] * a[i + 3];
        }
        float tw = tau * ((w0 + w1) + (w2 + w3));
#pragma unroll
        for (int i = 0; i < 64; ++i) a[i] -= tw * vr[i];

        // forward Q accumulation on own row: q -= tau*(q . v) * v
        float u0 = 0.f, u1 = 0.f, u2 = 0.f, u3 = 0.f;
#pragma unroll
        for (int j = 0; j < 64; j += 4) {
            u0 += q[j] * vr[j]; u1 += q[j + 1] * vr[j + 1];
            u2 += q[j + 2] * vr[j + 2]; u3 += q[j + 3] * vr[j + 3];
        }
        float tu = tau * ((u0 + u1) + (u2 + u3));
#pragma unroll
        for (int j = 0; j < 64; ++j) q[j] -= tu * vr[j];
    }

    // transpose through LDS for coalesced store (row-major qtab)
    __shared__ float tr[64 * 65];
#pragma unroll
    for (int j = 0; j < 64; ++j) tr[l * 65 + j] = q[j];   // (l+j)%32 banks: conflict-free
    __syncthreads();
    float* dst = qtab + v * 4096;
#pragma unroll
    for (int i = 0; i < 64; ++i) dst[i * 64 + l] = tr[i * 65 + l];  // coalesced
}

// ---------------- Kernel 2: chunk products of 16, one wave per chain ----------------
// grid = 1024 blocks x 64 threads. LDS layout: element (r,c) at float offset
// 64*r + 4*((c>>2) ^ (r>>3)) + (c&3)  — XOR granule swizzle, conflict-free for
// both row-fragment (A) and column-slice (B) ds_read_b128. No barriers: one
// wave per block, DS pipeline is in-order per wave.
__global__ __launch_bounds__(64) void scan1_kernel(const int* __restrict__ ids,
                                                   const float* __restrict__ qtab,
                                                   float* __restrict__ P) {
    __shared__ float Sb[4096];
    __shared__ float Qb[4096];
    const int t = threadIdx.x;
    const int lr = t >> 3, lc = t & 7;
    const int base = blockIdx.x << 4;   // (b*32+c)*16 == blockIdx*16

    float4 pf[16];
    // stage S = Q[ids[0]]
    {
        const float4* q0 = reinterpret_cast<const float4*>(qtab + (size_t)ids[base] * 4096);
#pragma unroll
        for (int m = 0; m < 16; ++m) pf[m] = q0[(m << 6) + t];
#pragma unroll
        for (int m = 0; m < 16; ++m) {
            const int r = 4 * m + (t >> 4);
            *reinterpret_cast<float4*>(&Sb[(r << 6) + (((t & 15) ^ (m >> 1)) << 2)]) = pf[m];
        }
    }
    // prefetch Q for step 1
    {
        const float4* q1 = reinterpret_cast<const float4*>(qtab + (size_t)ids[base + 1] * 4096);
#pragma unroll
        for (int m = 0; m < 16; ++m) pf[m] = q1[(m << 6) + t];
    }

#pragma unroll 1
    for (int step = 1; step < 16; ++step) {
        // commit prefetched Q to LDS
#pragma unroll
        for (int m = 0; m < 16; ++m) {
            const int r = 4 * m + (t >> 4);
            *reinterpret_cast<float4*>(&Qb[(r << 6) + (((t & 15) ^ (m >> 1)) << 2)]) = pf[m];
        }
        // issue next prefetch (covered by the matmul below)
        if (step + 1 < 16) {
            const float4* qx = reinterpret_cast<const float4*>(qtab + (size_t)ids[base + step + 1] * 4096);
#pragma unroll
            for (int m = 0; m < 16; ++m) pf[m] = qx[(m << 6) + t];
        }
        __builtin_amdgcn_sched_barrier(0);

        // S <- Qb @ S : 8x8 register tile per lane (lane grid 8 rows x 8 cols)
        float acc[8][8];
#pragma unroll
        for (int r = 0; r < 8; ++r)
#pragma unroll
            for (int c = 0; c < 8; ++c) acc[r][c] = 0.f;

#pragma unroll
        for (int k4 = 0; k4 < 16; ++k4) {
            float4 av[8];
#pragma unroll
            for (int rr = 0; rr < 8; ++rr)
                av[rr] = *reinterpret_cast<const float4*>(&Qb[((8 * lr + rr) << 6) + ((k4 ^ lr) << 2)]);
            float4 bv0[4], bv1[4];
#pragma unroll
            for (int kk = 0; kk < 4; ++kk) {
                const int kr = 4 * k4 + kk;
                const int K = kr >> 3;
                bv0[kk] = *reinterpret_cast<const float4*>(&Sb[(kr << 6) + (((2 * lc) ^ K) << 2)]);
                bv1[kk] = *reinterpret_cast<const float4*>(&Sb[(kr << 6) + (((2 * lc + 1) ^ K) << 2)]);
            }
#pragma unroll
            for (int rr = 0; rr < 8; ++rr) {
                const float* ar = reinterpret_cast<const float*>(&av[rr]);
#pragma unroll
                for (int kk = 0; kk < 4; ++kk) {
                    const float s = ar[kk];
                    const float4 b0 = bv0[kk], b1 = bv1[kk];
                    acc[rr][0] += s * b0.x; acc[rr][1] += s * b0.y;
                    acc[rr][2] += s * b0.z; acc[rr][3] += s * b0.w;
                    acc[rr][4] += s * b1.x; acc[rr][5] += s * b1.y;
                    acc[rr][6] += s * b1.z; acc[rr][7] += s * b1.w;
                }
            }
        }
        __builtin_amdgcn_sched_barrier(0);
        // write back (in-order DS: all reads above complete first)
#pragma unroll
        for (int rr = 0; rr < 8; ++rr) {
            const int r = 8 * lr + rr;
            *reinterpret_cast<float4*>(&Sb[(r << 6) + (((2 * lc) ^ lr) << 2)]) =
                make_float4(acc[rr][0], acc[rr][1], acc[rr][2], acc[rr][3]);
            *reinterpret_cast<float4*>(&Sb[(r << 6) + (((2 * lc + 1) ^ lr) << 2)]) =
                make_float4(acc[rr][4], acc[rr][5], acc[rr][6], acc[rr][7]);
        }
        __builtin_amdgcn_sched_barrier(0);
    }

    // unstage to P (row-major)
    float4* dst = reinterpret_cast<float4*>(P + (size_t)blockIdx.x * 4096);
#pragma unroll
    for (int m = 0; m < 16; ++m) {
        const int r = 4 * m + (t >> 4);
        dst[(m << 6) + t] =
            *reinterpret_cast<const float4*>(&Sb[(r << 6) + (((t & 15) ^ (m >> 1)) << 2)]);
    }
}

// ---------------- Kernel 3: products of 8 chunk-products ----------------
__global__ __launch_bounds__(256) void scan2_kernel(const float* __restrict__ P,
                                                    float* __restrict__ PP) {
    __shared__ float S[64 * LDP];
    __shared__ float Qn[64 * LDP];
    const int t = threadIdx.x;
    const int b = blockIdx.x >> 2;
    const int g = blockIdx.x & 3;
    const float* base = P + (size_t)(b * 32 + g * 8) * 4096;
    stage64(S, base, t);
    for (int m = 1; m < 8; ++m) {
        stage64(Qn, base + m * 4096, t);
        __syncthreads();
        mm64(S, Qn, t);
    }
    __syncthreads();
    unstage64(PP + (size_t)blockIdx.x * 4096, S, t);
}

// ---------------- Kernel 4: final 4-way product + readout ----------------
__global__ __launch_bounds__(256) void scan3_readout_kernel(const float* __restrict__ PP,
                                                            const float* __restrict__ W1,
                                                            const float* __restrict__ b1,
                                                            const float* __restrict__ W2,
                                                            const float* __restrict__ b2,
                                                            float* __restrict__ out) {
    __shared__ float S[64 * LDP];
    __shared__ float Qn[64 * LDP];
    __shared__ float hl[64];
    const int t = threadIdx.x;
    const int b = blockIdx.x;
    const float* base = PP + (size_t)b * 4 * 4096;
    stage64(S, base, t);
    for (int m = 1; m < 4; ++m) {
        stage64(Qn, base + m * 4096, t);
        __syncthreads();
        mm64(S, Qn, t);
    }
    __syncthreads();

    const int jg = t & 15;
    const int qd = t >> 4;
    float hp[4] = {0.f, 0.f, 0.f, 0.f};
    const int j4 = jg << 2;
#pragma unroll 4
    for (int m = 0; m < 256; ++m) {
        const int n = (qd << 8) + m;
        const float vn = S[(n >> 6) * LDP + (n & 63)];
        const float4 w = *reinterpret_cast<const float4*>(&W1[n * 64 + j4]);
        hp[0] += vn * w.x; hp[1] += vn * w.y; hp[2] += vn * w.z; hp[3] += vn * w.w;
    }
    float* hpart = Qn;
    *reinterpret_cast<float4*>(&hpart[qd * 64 + j4]) = make_float4(hp[0], hp[1], hp[2], hp[3]);
    __syncthreads();
    if (t < 64) {
        float h = b1[t];
#pragma unroll
        for (int q2 = 0; q2 < 16; ++q2) h += hpart[q2 * 64 + t];
        hl[t] = fmaxf(h, 0.f);
    }
    __syncthreads();
    if (t < 60) {
        float acc = b2[t];
#pragma unroll
        for (int j = 0; j < 64; ++j) acc += hl[j] * W2[j * 60 + t];
        out[b * 60 + t] = acc;
    }
}

// ---------------- launch ----------------
extern "C" void kernel_launch(void* const* d_in, const int* in_sizes, int n_in,
                              void* d_out, int out_size, void* d_ws, size_t ws_size,
                              hipStream_t stream) {
    (void)in_sizes; (void)n_in; (void)out_size; (void)ws_size;
    const int*   ids  = (const int*)d_in[0];
    const float* repr = (const float*)d_in[1];
    const float* W1   = (const float*)d_in[2];
    const float* b1   = (const float*)d_in[3];
    const float* W2   = (const float*)d_in[4];
    const float* b2   = (const float*)d_in[5];
    float* out = (float*)d_out;

    char* ws = (char*)d_ws;
    float* qtab = (float*)(ws);                              // 60*4096*4  = 0.94 MB
    float* P    = (float*)(ws + (1u << 20));                 // 1024*4096*4 = 16 MB
    float* PP   = (float*)(ws + (1u << 20) + (16u << 20));   // 128*4096*4  = 2 MB

    qr_kernel<<<60, 64, 0, stream>>>(repr, qtab);
    scan1_kernel<<<1024, 64, 0, stream>>>(ids, qtab, P);
    scan2_kernel<<<128, 256, 0, stream>>>(P, PP);
    scan3_readout_kernel<<<32, 256, 0, stream>>>(PP, W1, b1, W2, b2, out);
}

// Round 4
// 266.375 us; speedup vs baseline: 1.6807x; 1.6807x over previous
//
#include <hip/hip_runtime.h>

// B=32, T=512, D=64, V=60
// inputs: [0] input_ids int32 [32*512], [1] repr_tab f32 [60*64*64],
//         [2] W1 f32 [4096*64], [3] b1 f32 [64], [4] W2 f32 [64*60], [5] b2 f32 [60]
// output: logits f32 [32*60]
//
// Pipeline:
//   qr_kernel    (60 blocks):  Householder QR (LAPACK sign convention), emits Q as
//                              bf16 hi/lo planes in A-layout (row-granules) and
//                              B-layout (col-granules), granule-XOR-swizzled.
//   scan1_kernel (512 blocks): chains of 32 Q-factors; S in LDS (bf16 hi/lo, B-layout);
//                              A-fragments direct global->reg, prefetched; 3-term
//                              split-bf16 MFMA via COMPILER BUILTIN (hazards handled).
//   scan2_kernel (32 blocks):  product of 16 chunk-products per batch + fused readout.
//
// Layout glossary (all bf16 planes are 4096 shorts; hi plane at +0, lo at +4096):
//   granule(row r, G=k>>3) at short offset r*64 + ((G ^ (r&7) ^ (r>>3)) << 3) + (k&7)
//   A-plane: r = matrix row m, k = column index   (MFMA A operand: 8 consecutive k)
//   B-plane: r = matrix col n, k = row index      (MFMA B operand: 8 consecutive k)

typedef short v8s __attribute__((ext_vector_type(8)));
typedef short v4s __attribute__((ext_vector_type(4)));
typedef float v16f __attribute__((ext_vector_type(16)));
typedef __bf16 bf16x8 __attribute__((ext_vector_type(8)));

// f32 -> (hi, lo) bf16 with RNE, branch-free bit tricks.
__device__ __forceinline__ void split_one(float f, unsigned& hi, unsigned& lo) {
    unsigned u = __float_as_uint(f);
    unsigned rh = u + 0x7fffu + ((u >> 16) & 1u);
    float fh = __uint_as_float(rh & 0xffff0000u);
    hi = rh >> 16;
    float g = f - fh;                     // exact (Sterbenz)
    unsigned ul = __float_as_uint(g);
    unsigned rl = ul + 0x7fffu + ((ul >> 16) & 1u);
    lo = rl >> 16;
}

__device__ __forceinline__ void split4(const float* f, v4s& hi4, v4s& lo4) {
#pragma unroll
    for (int r = 0; r < 4; ++r) {
        unsigned h, l;
        split_one(f[r], h, l);
        hi4[r] = (short)h;
        lo4[r] = (short)l;
    }
}

__device__ __forceinline__ void split8(const float* f, v8s& hi8, v8s& lo8) {
#pragma unroll
    for (int r = 0; r < 8; ++r) {
        unsigned h, l;
        split_one(f[r], h, l);
        hi8[r] = (short)h;
        lo8[r] = (short)l;
    }
}

// ---------------- Kernel 1: barrier-free one-wave Householder QR ----------------
__global__ __launch_bounds__(64) void qr_kernel(const float* __restrict__ repr,
                                                unsigned short* __restrict__ qtabA,
                                                unsigned short* __restrict__ qtabB) {
    const int l = threadIdx.x;
    const int v = blockIdx.x;
    const float* src = repr + v * 4096;

    float a[64];   // column l of A
    float q[64];   // row l of Q accumulator
#pragma unroll
    for (int i = 0; i < 64; ++i) a[i] = src[i * 64 + l];
#pragma unroll
    for (int i = 0; i < 64; ++i) q[i] = (i == l) ? 1.f : 0.f;

#pragma unroll 1
    for (int k = 0; k < 64; ++k) {
        float vr[64];
#pragma unroll
        for (int i = 0; i < 64; ++i) vr[i] = __shfl(a[i], k);

        float s0 = 0.f, s1 = 0.f, s2 = 0.f, s3 = 0.f;
#pragma unroll
        for (int i = 0; i < 64; i += 4) {
            s0 += (i     > k) ? vr[i]     * vr[i]     : 0.f;
            s1 += (i + 1 > k) ? vr[i + 1] * vr[i + 1] : 0.f;
            s2 += (i + 2 > k) ? vr[i + 2] * vr[i + 2] : 0.f;
            s3 += (i + 3 > k) ? vr[i + 3] * vr[i + 3] : 0.f;
        }
        float sigma = (s0 + s1) + (s2 + s3);
        float al = 0.f;
#pragma unroll
        for (int i = 0; i < 64; ++i) al = (i == k) ? vr[i] : al;

        float beta, tau, scl;
        if (sigma == 0.f) { beta = al; tau = 0.f; scl = 0.f; }
        else {
            beta = -copysignf(sqrtf(al * al + sigma), al);
            tau = (beta - al) / beta;
            scl = 1.f / (al - beta);
        }

#pragma unroll
        for (int i = 0; i < 64; ++i) vr[i] = (i < k) ? 0.f : ((i == k) ? 1.f : vr[i] * scl);

        float w0 = 0.f, w1 = 0.f, w2 = 0.f, w3 = 0.f;
#pragma unroll
        for (int i = 0; i < 64; i += 4) {
            w0 += vr[i] * a[i]; w1 += vr[i + 1] * a[i + 1];
            w2 += vr[i + 2] * a[i + 2]; w3 += vr[i + 3] * a[i + 3];
        }
        float tw = tau * ((w0 + w1) + (w2 + w3));
#pragma unroll
        for (int i = 0; i < 64; ++i) a[i] -= tw * vr[i];

        float u0 = 0.f, u1 = 0.f, u2 = 0.f, u3 = 0.f;
#pragma unroll
        for (int j = 0; j < 64; j += 4) {
            u0 += q[j] * vr[j]; u1 += q[j + 1] * vr[j + 1];
            u2 += q[j + 2] * vr[j + 2]; u3 += q[j + 3] * vr[j + 3];
        }
        float tu = tau * ((u0 + u1) + (u2 + u3));
#pragma unroll
        for (int j = 0; j < 64; ++j) q[j] -= tu * vr[j];
    }

    // ---- A-plane: lane l holds row l of Q ----
    {
        unsigned short* dstA = qtabA + (size_t)v * 8192 + (size_t)l * 64;
#pragma unroll
        for (int G = 0; G < 8; ++G) {
            v8s hi8, lo8;
            split8(&q[8 * G], hi8, lo8);
            const int sl = (G ^ (l & 7) ^ (l >> 3)) << 3;
            *reinterpret_cast<v8s*>(&dstA[sl]) = hi8;
            *reinterpret_cast<v8s*>(&dstA[4096 + sl]) = lo8;
        }
    }
    // ---- transpose through LDS, then B-plane: lane l holds column l of Q ----
    __shared__ float tr[64 * 65];
#pragma unroll
    for (int j = 0; j < 64; ++j) tr[l * 65 + j] = q[j];
    __syncthreads();
    {
        unsigned short* dstB = qtabB + (size_t)v * 8192 + (size_t)l * 64;
#pragma unroll
        for (int G = 0; G < 8; ++G) {
            float cv[8];
#pragma unroll
            for (int i = 0; i < 8; ++i) cv[i] = tr[(8 * G + i) * 65 + l];
            v8s hi8, lo8;
            split8(cv, hi8, lo8);
            const int sl = (G ^ (l & 7) ^ (l >> 3)) << 3;
            *reinterpret_cast<v8s*>(&dstB[sl]) = hi8;
            *reinterpret_cast<v8s*>(&dstB[4096 + sl]) = lo8;
        }
    }
}

// ---------------- Kernel 2: chains of 32 factors, 4 waves, MFMA ----------------
__global__ __launch_bounds__(256) void scan1_kernel(const int* __restrict__ ids,
                                                    const unsigned short* __restrict__ qtabA,
                                                    const unsigned short* __restrict__ qtabB,
                                                    unsigned short* __restrict__ PA,
                                                    unsigned short* __restrict__ PB) {
    __shared__ unsigned short SBm[8192];   // hi plane [0,4096), lo plane [4096,8192)
    __shared__ int ids_s[32];
    const int t = threadIdx.x;
    const int l = t & 63, w = t >> 6;
    const int rw = w >> 1, cw = w & 1, h = l >> 5;
    const int b = blockIdx.x >> 4, c = blockIdx.x & 15;
    if (t < 32) ids_s[t] = ids[b * 512 + c * 32 + t];

    const int m = 32 * rw + (l & 31);   // A-operand row
    const int n = 32 * cw + (l & 31);   // B-operand / D col
    int aoff[8], boff[4], doff[4];
#pragma unroll
    for (int s4 = 0; s4 < 4; ++s4) {
        const int G = 2 * s4 + h;
        aoff[s4]     = m * 64 + ((G ^ (m & 7) ^ (m >> 3)) << 3);
        aoff[s4 + 4] = aoff[s4] + 4096;
        boff[s4]     = n * 64 + ((G ^ (n & 7) ^ (n >> 3)) << 3);
    }
#pragma unroll
    for (int rg = 0; rg < 4; ++rg)
        doff[rg] = n * 64 + (((4 * rw + rg) ^ (n & 7) ^ (n >> 3)) << 3) + 4 * h;

    __syncthreads();   // ids_s visible

    // stage S = Q[ids[0]] (B-layout, linear copy)
    {
        const unsigned short* srcB = qtabB + (size_t)ids_s[0] * 8192;
#pragma unroll
        for (int u = 0; u < 4; ++u)
            *reinterpret_cast<v8s*>(&SBm[t * 32 + u * 8]) =
                *reinterpret_cast<const v8s*>(&srcB[t * 32 + u * 8]);
    }
    // prefetch A-fragments for factor 1
    bf16x8 cur[8], nxt[8];
    {
        const unsigned short* ga = qtabA + (size_t)ids_s[1] * 8192;
#pragma unroll
        for (int qv = 0; qv < 8; ++qv)
            cur[qv] = *reinterpret_cast<const bf16x8*>(&ga[aoff[qv]]);
    }
    __syncthreads();   // SBm staged

#pragma unroll 1
    for (int j = 1; j < 32; ++j) {
        const int vn = ids_s[(j < 31) ? (j + 1) : 31];
        const unsigned short* ga = qtabA + (size_t)vn * 8192;
#pragma unroll
        for (int qv = 0; qv < 8; ++qv)
            nxt[qv] = *reinterpret_cast<const bf16x8*>(&ga[aoff[qv]]);

        v16f acc;
#pragma unroll
        for (int z = 0; z < 16; ++z) acc[z] = 0.f;

#pragma unroll
        for (int s4 = 0; s4 < 4; ++s4) {
            bf16x8 bh = *reinterpret_cast<const bf16x8*>(&SBm[boff[s4]]);
            bf16x8 bl = *reinterpret_cast<const bf16x8*>(&SBm[4096 + boff[s4]]);
            acc = __builtin_amdgcn_mfma_f32_32x32x16_bf16(cur[s4 + 4], bh, acc, 0, 0, 0); // lo*hi
            acc = __builtin_amdgcn_mfma_f32_32x32x16_bf16(cur[s4], bl, acc, 0, 0, 0);     // hi*lo
            acc = __builtin_amdgcn_mfma_f32_32x32x16_bf16(cur[s4], bh, acc, 0, 0, 0);     // hi*hi
        }
        __syncthreads();   // all B-reads done before S is overwritten
#pragma unroll
        for (int rg = 0; rg < 4; ++rg) {
            float f[4];
#pragma unroll
            for (int r = 0; r < 4; ++r) f[r] = acc[4 * rg + r];
            v4s hi4, lo4;
            split4(f, hi4, lo4);
            *reinterpret_cast<v4s*>(&SBm[doff[rg]]) = hi4;
            *reinterpret_cast<v4s*>(&SBm[4096 + doff[rg]]) = lo4;
        }
        __syncthreads();   // new S visible
#pragma unroll
        for (int qv = 0; qv < 8; ++qv) cur[qv] = nxt[qv];
    }

    if (c == 0) {
        // B-layout copy (linear) for scan2's initial state
        unsigned short* dst = PB + (size_t)b * 8192;
#pragma unroll
        for (int u = 0; u < 4; ++u)
            *reinterpret_cast<v8s*>(&dst[t * 32 + u * 8]) =
                *reinterpret_cast<const v8s*>(&SBm[t * 32 + u * 8]);
    } else {
        // gather-transpose SBm (B-layout) -> A-layout global
        unsigned short* dst = PA + (size_t)(b * 16 + c) * 8192;
        const int mm = t & 63;
#pragma unroll
        for (int u = 0; u < 4; ++u) {
            const int p = u & 1;
            const int G = 2 * (t >> 6) + (u >> 1);
            v8s pk;
#pragma unroll
            for (int i = 0; i < 8; ++i)
                pk[i] = (short)SBm[p * 4096 + (8 * G + i) * 64 +
                                   (((mm >> 3) ^ i ^ G) << 3) + (mm & 7)];
            *reinterpret_cast<v8s*>(
                &dst[p * 4096 + mm * 64 + ((G ^ (mm & 7) ^ (mm >> 3)) << 3)]) = pk;
        }
    }
}

// ---------------- Kernel 3: per-batch product of 16 chunks + readout ----------------
__global__ __launch_bounds__(256) void scan2_kernel(const unsigned short* __restrict__ PA,
                                                    const unsigned short* __restrict__ PB,
                                                    const float* __restrict__ W1,
                                                    const float* __restrict__ b1,
                                                    const float* __restrict__ W2,
                                                    const float* __restrict__ b2,
                                                    float* __restrict__ out) {
    __shared__ unsigned short SBm[8192];
    __shared__ float Sf[64 * 68];
    __shared__ float hl[64];
    const int t = threadIdx.x;
    const int l = t & 63, w = t >> 6;
    const int rw = w >> 1, cw = w & 1, h = l >> 5;
    const int b = blockIdx.x;

    const int m = 32 * rw + (l & 31);
    const int n = 32 * cw + (l & 31);
    int aoff[8], boff[4], doff[4];
#pragma unroll
    for (int s4 = 0; s4 < 4; ++s4) {
        const int G = 2 * s4 + h;
        aoff[s4]     = m * 64 + ((G ^ (m & 7) ^ (m >> 3)) << 3);
        aoff[s4 + 4] = aoff[s4] + 4096;
        boff[s4]     = n * 64 + ((G ^ (n & 7) ^ (n >> 3)) << 3);
    }
#pragma unroll
    for (int rg = 0; rg < 4; ++rg)
        doff[rg] = n * 64 + (((4 * rw + rg) ^ (n & 7) ^ (n >> 3)) << 3) + 4 * h;

    // stage S = chunk(b*16 + 0) from PB
    {
        const unsigned short* srcB = PB + (size_t)b * 8192;
#pragma unroll
        for (int u = 0; u < 4; ++u)
            *reinterpret_cast<v8s*>(&SBm[t * 32 + u * 8]) =
                *reinterpret_cast<const v8s*>(&srcB[t * 32 + u * 8]);
    }
    bf16x8 cur[8], nxt[8];
    {
        const unsigned short* ga = PA + (size_t)(b * 16 + 1) * 8192;
#pragma unroll
        for (int qv = 0; qv < 8; ++qv)
            cur[qv] = *reinterpret_cast<const bf16x8*>(&ga[aoff[qv]]);
    }
    __syncthreads();

#pragma unroll 1
    for (int j = 1; j < 15; ++j) {
        const unsigned short* ga = PA + (size_t)(b * 16 + j + 1) * 8192;
#pragma unroll
        for (int qv = 0; qv < 8; ++qv)
            nxt[qv] = *reinterpret_cast<const bf16x8*>(&ga[aoff[qv]]);

        v16f acc;
#pragma unroll
        for (int z = 0; z < 16; ++z) acc[z] = 0.f;
#pragma unroll
        for (int s4 = 0; s4 < 4; ++s4) {
            bf16x8 bh = *reinterpret_cast<const bf16x8*>(&SBm[boff[s4]]);
            bf16x8 bl = *reinterpret_cast<const bf16x8*>(&SBm[4096 + boff[s4]]);
            acc = __builtin_amdgcn_mfma_f32_32x32x16_bf16(cur[s4 + 4], bh, acc, 0, 0, 0);
            acc = __builtin_amdgcn_mfma_f32_32x32x16_bf16(cur[s4], bl, acc, 0, 0, 0);
            acc = __builtin_amdgcn_mfma_f32_32x32x16_bf16(cur[s4], bh, acc, 0, 0, 0);
        }
        __syncthreads();
#pragma unroll
        for (int rg = 0; rg < 4; ++rg) {
            float f[4];
#pragma unroll
            for (int r = 0; r < 4; ++r) f[r] = acc[4 * rg + r];
            v4s hi4, lo4;
            split4(f, hi4, lo4);
            *reinterpret_cast<v4s*>(&SBm[doff[rg]]) = hi4;
            *reinterpret_cast<v4s*>(&SBm[4096 + doff[rg]]) = lo4;
        }
        __syncthreads();
#pragma unroll
        for (int qv = 0; qv < 8; ++qv) cur[qv] = nxt[qv];
    }

    // final step (j = 15): write result to Sf as f32
    {
        v16f acc;
#pragma unroll
        for (int z = 0; z < 16; ++z) acc[z] = 0.f;
#pragma unroll
        for (int s4 = 0; s4 < 4; ++s4) {
            bf16x8 bh = *reinterpret_cast<const bf16x8*>(&SBm[boff[s4]]);
            bf16x8 bl = *reinterpret_cast<const bf16x8*>(&SBm[4096 + boff[s4]]);
            acc = __builtin_amdgcn_mfma_f32_32x32x16_bf16(cur[s4 + 4], bh, acc, 0, 0, 0);
            acc = __builtin_amdgcn_mfma_f32_32x32x16_bf16(cur[s4], bl, acc, 0, 0, 0);
            acc = __builtin_amdgcn_mfma_f32_32x32x16_bf16(cur[s4], bh, acc, 0, 0, 0);
        }
#pragma unroll
        for (int rg = 0; rg < 4; ++rg)
#pragma unroll
            for (int r = 0; r < 4; ++r)
                Sf[(32 * rw + 8 * rg + 4 * h + r) * 68 + n] = acc[4 * rg + r];
    }
    __syncthreads();

    // readout: h = relu(vec(S) @ W1 + b1); logits = h @ W2 + b2
    const int jg = t & 15, qd = t >> 4, j4 = jg << 2;
    float hp[4] = {0.f, 0.f, 0.f, 0.f};
#pragma unroll 4
    for (int mm = 0; mm < 256; ++mm) {
        const int nn = (qd << 8) + mm;
        const float vn = Sf[(nn >> 6) * 68 + (nn & 63)];
        const float4 wv = *reinterpret_cast<const float4*>(&W1[nn * 64 + j4]);
        hp[0] += vn * wv.x; hp[1] += vn * wv.y; hp[2] += vn * wv.z; hp[3] += vn * wv.w;
    }
    float* hpart = reinterpret_cast<float*>(SBm);   // SBm no longer needed
    *reinterpret_cast<float4*>(&hpart[qd * 64 + j4]) = make_float4(hp[0], hp[1], hp[2], hp[3]);
    __syncthreads();
    if (t < 64) {
        float hh = b1[t];
#pragma unroll
        for (int q2 = 0; q2 < 16; ++q2) hh += hpart[q2 * 64 + t];
        hl[t] = fmaxf(hh, 0.f);
    }
    __syncthreads();
    if (t < 60) {
        float a2 = b2[t];
#pragma unroll
        for (int jj = 0; jj < 64; ++jj) a2 += hl[jj] * W2[jj * 60 + t];
        out[b * 60 + t] = a2;
    }
}

// ---------------- launch ----------------
extern "C" void kernel_launch(void* const* d_in, const int* in_sizes, int n_in,
                              void* d_out, int out_size, void* d_ws, size_t ws_size,
                              hipStream_t stream) {
    (void)in_sizes; (void)n_in; (void)out_size; (void)ws_size;
    const int*   ids  = (const int*)d_in[0];
    const float* repr = (const float*)d_in[1];
    const float* W1   = (const float*)d_in[2];
    const float* b1   = (const float*)d_in[3];
    const float* W2   = (const float*)d_in[4];
    const float* b2   = (const float*)d_in[5];
    float* out = (float*)d_out;

    char* ws = (char*)d_ws;
    unsigned short* qtabA = (unsigned short*)(ws);                   // 60*16KB  < 1MB
    unsigned short* qtabB = (unsigned short*)(ws + (1u << 20));      // 60*16KB  < 1MB
    unsigned short* PA    = (unsigned short*)(ws + (2u << 20));      // 512*16KB = 8MB
    unsigned short* PB    = (unsigned short*)(ws + (10u << 20));     // 32*16KB  = 512KB

    qr_kernel<<<60, 64, 0, stream>>>(repr, qtabA, qtabB);
    scan1_kernel<<<512, 256, 0, stream>>>(ids, qtabA, qtabB, PA, PB);
    scan2_kernel<<<32, 256, 0, stream>>>(PA, PB, W1, b1, W2, b2, out);
}